// Round 1
// baseline (490.272 us; speedup 1.0000x reference)
//
#include <hip/hip_runtime.h>

// GeodesicShooting: separable Gaussian blur (k=9, zero-pad) over a [160^3,3]
// f32 velocity field, then 6 scaling-and-squaring steps:
//   v <- v + trilinear_sample(v, v + identity_grid)   (align_corners=True, zeros pad)

constexpr int W = 160, H = 160, D = 160;
constexpr int NVOX = W * H * D;           // 4,096,000 voxels
constexpr int NSTEPS = 6;                 // setup_inputs: n_steps = 6

// ---------------- blur along one axis ----------------
// coordinate along axis = (i / div) % len ; neighbor step = strideVox voxels
__global__ void blur_axis_kernel(const float* __restrict__ in, float* __restrict__ out,
                                 const float* __restrict__ kern, int klen,
                                 int len, int div, int strideVox, float scale)
{
    int i = blockIdx.x * blockDim.x + threadIdx.x;
    if (i >= NVOX) return;
    int c = (i / div) % len;
    int R = (klen - 1) / 2;
    float ax = 0.f, ay = 0.f, az = 0.f;
    for (int t = 0; t < klen; ++t) {
        int cc = c + t - R;
        if (cc < 0 || cc >= len) continue;           // zero padding
        const float* p = in + (size_t)(i + (t - R) * strideVox) * 3;
        float w = kern[t];
        ax = fmaf(w, p[0], ax);
        ay = fmaf(w, p[1], ay);
        az = fmaf(w, p[2], az);
    }
    float* q = out + (size_t)i * 3;
    q[0] = ax * scale;
    q[1] = ay * scale;
    q[2] = az * scale;
}

// ---------------- one scaling-and-squaring step ----------------
// out[p] = v[p] + sample(v, voxel_coords(v[p] + grid[p]))
__global__ void step_kernel(const float* __restrict__ v, const float* __restrict__ grd,
                            float* __restrict__ out)
{
    int i = blockIdx.x * blockDim.x + threadIdx.x;
    if (i >= NVOX) return;

    size_t b = (size_t)i * 3;
    float vx = v[b + 0], vy = v[b + 1], vz = v[b + 2];
    float gx = grd[b + 0], gy = grd[b + 1], gz = grd[b + 2];

    // reference: x = ((grid_x + v_x) + 1) * 0.5 * (W-1)  (align_corners=True)
    float sx = ((vx + gx) + 1.0f) * 0.5f * (float)(W - 1);
    float sy = ((vy + gy) + 1.0f) * 0.5f * (float)(H - 1);
    float sz = ((vz + gz) + 1.0f) * 0.5f * (float)(D - 1);

    float fx = floorf(sx), fy = floorf(sy), fz = floorf(sz);
    float wx1 = sx - fx, wy1 = sy - fy, wz1 = sz - fz;
    int x0 = (int)fx, y0 = (int)fy, z0 = (int)fz;

    float wxs[2] = {1.0f - wx1, wx1};
    float wys[2] = {1.0f - wy1, wy1};
    float wzs[2] = {1.0f - wz1, wz1};

    float ax = 0.f, ay = 0.f, az = 0.f;
#pragma unroll
    for (int iz = 0; iz < 2; ++iz) {
        int zc = z0 + iz;
        if (zc < 0 || zc > D - 1) continue;          // zeros padding: skip invalid corner
#pragma unroll
        for (int iy = 0; iy < 2; ++iy) {
            int yc = y0 + iy;
            if (yc < 0 || yc > H - 1) continue;
            float wzy = wzs[iz] * wys[iy];
#pragma unroll
            for (int ix = 0; ix < 2; ++ix) {
                int xc = x0 + ix;
                if (xc < 0 || xc > W - 1) continue;
                float wgt = wzy * wxs[ix];
                const float* p = v + ((size_t)(zc * H + yc) * W + xc) * 3;
                ax = fmaf(wgt, p[0], ax);
                ay = fmaf(wgt, p[1], ay);
                az = fmaf(wgt, p[2], az);
            }
        }
    }
    out[b + 0] = vx + ax;
    out[b + 1] = vy + ay;
    out[b + 2] = vz + az;
}

extern "C" void kernel_launch(void* const* d_in, const int* in_sizes, int n_in,
                              void* d_out, int out_size, void* d_ws, size_t ws_size,
                              hipStream_t stream)
{
    const float* vel  = (const float*)d_in[0];
    const float* grd  = (const float*)d_in[1];
    const float* gk   = (const float*)d_in[2];
    int klen = in_sizes[2];                 // 9 for sigma=1, trunc=4

    float* out = (float*)d_out;
    float* tmp = (float*)d_ws;              // one [NVOX,3] f32 buffer (49.2 MB)

    const int threads = 256;
    const int blocks = (NVOX + threads - 1) / threads;
    const float scale = 1.0f / (float)(1 << NSTEPS);   // 2^-6

    // separable blur, reference order: D axis, then H, then W (scale fused last)
    blur_axis_kernel<<<blocks, threads, 0, stream>>>(vel, out, gk, klen, D, W * H, W * H, 1.0f);
    blur_axis_kernel<<<blocks, threads, 0, stream>>>(out, tmp, gk, klen, H, W, W, 1.0f);
    blur_axis_kernel<<<blocks, threads, 0, stream>>>(tmp, out, gk, klen, W, 1, 1, scale);

    // 6 squaring steps, ping-pong out -> tmp -> out ... -> out
    const float* src = out;
    float* dst = tmp;
    for (int s = 0; s < NSTEPS; ++s) {
        step_kernel<<<blocks, threads, 0, stream>>>(src, grd, dst);
        const float* nsrc = dst;
        dst = (float*)(s % 2 == 0 ? (void*)out : (void*)tmp);
        src = nsrc;
    }
    // after step 6 the result is in d_out
}